// Round 10
// baseline (243.808 us; speedup 1.0000x reference)
//
#include <hip/hip_runtime.h>
#include <cstdint>
#include <cstddef>

// Problem constants
#define Bc  4
#define Sc  2048
#define Dc  1024
#define Hc  16
#define DDc 64
#define Nc  256   // pooled length

typedef unsigned short u16;
typedef unsigned int   u32;
typedef __bf16 bf16_t;
typedef bf16_t bf16x8 __attribute__((ext_vector_type(8)));
typedef float  f32x4  __attribute__((ext_vector_type(4)));

__device__ __forceinline__ u16 f2bf(float x) {
    u32 u = __float_as_uint(x);
    return (u16)((u + 0x7FFFu + ((u >> 16) & 1u)) >> 16);   // RNE
}
__device__ __forceinline__ u32 pack2(float a, float b) {
    return (u32)f2bf(a) | ((u32)f2bf(b) << 16);
}
__device__ __forceinline__ uint2 pack4v(f32x4 x) {
    return make_uint2(pack2(x[0], x[1]), pack2(x[2], x[3]));
}
__device__ __forceinline__ float bf2f(u16 x) {
    return __uint_as_float((u32)x << 16);
}

// async global->LDS, 16B per lane (global src per-lane; LDS dest = wave-uniform base + lane*16)
__device__ __forceinline__ void gload_lds16(const void* gp, void* lp) {
    __builtin_amdgcn_global_load_lds(
        reinterpret_cast<const __attribute__((address_space(1))) void*>(
            reinterpret_cast<uintptr_t>(gp)),
        reinterpret_cast<__attribute__((address_space(3))) void*>(
            reinterpret_cast<uintptr_t>(lp)),
        16, 0, 0);
}

// ---- 1-wave GEMM building blocks (64x64 tile, BK=64, granule-swizzled LDS) ----
__device__ __forceinline__ void stage64(const char* src, size_t kb, u16* lds,
                                        int lane, size_t rstride) {
    const int rowoff = lane >> 3;                       // 0..7
    const int srcg   = ((lane & 7) ^ (rowoff & 7)) * 16;
    const char* s0 = src + kb + (size_t)srcg;
    #pragma unroll
    for (int i = 0; i < 8; ++i)
        gload_lds16(s0 + (size_t)(8 * i + rowoff) * rstride,
                    (char*)lds + i * 1024);             // wave-uniform dest base
}

__device__ __forceinline__ void frag_read(const u16* lds, int mi, int quad,
                                          bf16x8 f[4][2]) {
    const int key = mi & 7;                             // (i*16+mi)&7 == mi&7
    #pragma unroll
    for (int i = 0; i < 4; ++i)
        #pragma unroll
        for (int kc = 0; kc < 2; ++kc) {
            int g = (kc * 4 + quad) ^ key;
            f[i][kc] = *(const bf16x8*)(lds + (i * 16 + mi) * 64 + g * 8);
        }
}

// ================= launch 1: weight prep + bias + WupT =================
// blocks [0,1024)    : weight prep (z = bid>>8, k0 = ((bid>>4)&15)*64, n0 = (bid&15)*64)
// blocks [1024,1036) : bias table
// block  1036        : Wup transpose -> WupT bf16 [dp][d]
__global__ __launch_bounds__(256) void prep_misc(
    const float* __restrict__ Wq, const float* __restrict__ Wk,
    const float* __restrict__ Wv, const float* __restrict__ Wc,
    const float* __restrict__ Wup,
    const float* __restrict__ wcq, const float* __restrict__ wck, const float* __restrict__ wcv,
    const float* __restrict__ bcq, const float* __restrict__ bck, const float* __restrict__ bcv,
    const float* __restrict__ bq,  const float* __restrict__ bk,  const float* __restrict__ bv,
    u16* __restrict__ Wt3, u16* __restrict__ Wtc, float* __restrict__ biasT,
    u16* __restrict__ WupT)
{
    __shared__ float T[64][65];
    const int bid = blockIdx.x;
    const int tid = threadIdx.x;

    if (bid < 1024) {
        const int z = bid >> 8;
        const float* W = (z == 0) ? Wq : (z == 1) ? Wk : (z == 2) ? Wv : Wc;
        const int k0 = ((bid >> 4) & 15) * 64, n0 = (bid & 15) * 64;
        const int c = tid & 63, r4 = tid >> 6;
        #pragma unroll
        for (int i = 0; i < 16; ++i) {
            int r = i * 4 + r4;
            T[r][c] = W[(size_t)(k0 + r) * 1024 + n0 + c];
        }
        __syncthreads();
        if (z < 3) {
            const float* wc = (z == 0) ? wcq : (z == 1) ? wck : wcv;
            const float fs = 0.125f * ((z == 2) ? 1.0f : 0.35355339059327373f);
            u16* dst0 = Wt3 + (size_t)z * 3145728;
            #pragma unroll
            for (int i = 0; i < 16; ++i) {
                int r = i * 4 + r4;
                int n = n0 + r;
                float w0 = wc[n], w1 = wc[1024 + n], w2 = wc[2048 + n];
                float s2 = fs * w2, s1 = s2 + fs * w1, s0 = s1 + fs * w0;
                float x = T[c][r];
                u16* dst = dst0 + (size_t)n * 3072 + k0 + c;
                dst[0]    = f2bf(x * s0);
                dst[1024] = f2bf(x * s1);
                dst[2048] = f2bf(x * s2);
            }
        } else {
            #pragma unroll
            for (int i = 0; i < 16; ++i) {
                int r = i * 4 + r4;
                Wtc[(size_t)(n0 + r) * 1024 + k0 + c] = f2bf(T[c][r]);
            }
        }
        return;
    }

    if (bid < 1036) {
        int gid = (bid - 1024) * 256 + tid;   // over 3*1024
        int c = gid & 1023, z = gid >> 10;
        const float* wc    = (z == 0) ? wcq : (z == 1) ? wck : wcv;
        const float* bconv = (z == 0) ? bcq : (z == 1) ? bck : bcv;
        const float* bl    = (z == 0) ? bq  : (z == 1) ? bk  : bv;
        const float nrm = (z == 2) ? 1.0f : 0.35355339059327373f;
        float w0 = wc[c], w1 = wc[1024 + c], w2 = wc[2048 + c];
        float bc_ = bconv[c], bl_ = bl[c];
        float* dst = biasT + (size_t)z * 3072 + c;
        dst[0]    = 0.125f * (bc_ + nrm * bl_ * w2);
        dst[1024] = 0.125f * (8.f * bc_ + nrm * bl_ * (7.f * w0 + 8.f * w1 + 8.f * w2));
        dst[2048] = 0.125f * (8.f * bc_ + nrm * bl_ * 8.f * (w0 + w1 + w2));
        return;
    }

    // Wup transpose: WupT[dp][d] = Wup[d][dp], bf16
    const int c = tid & 63, r4 = tid >> 6;
    #pragma unroll
    for (int i = 0; i < 16; ++i) {
        int r = i * 4 + r4;
        T[r][c] = Wup[r * 64 + c];
    }
    __syncthreads();
    #pragma unroll
    for (int i = 0; i < 16; ++i) {
        int r = i * 4 + r4;
        WupT[r * 64 + c] = f2bf(T[c][r]);
    }
}

// ================= launch 2: sliding-window staging =================
// One block per (inp, b, chunk of 8 t-outputs). 18-row x 4KB LDS ring (72KB).
// Each wave owns a private 1KB column segment of every row -> no barriers.
// Steady state per step t: DMA the 8 new rows of window t+1 (slots s0+10..s0+17),
// s_waitcnt vmcnt(11) (8 new loads + 3 prior stores outstanding; window-t rows
// are older, hence complete), consume rows 8t-9..8t from slots s0..s0+9, store.
// Read amplification 66/64 = 1.03x (was 1.25x); identical sum tree -> same A3.
__global__ __launch_bounds__(256) void stage_slide(
    const float* __restrict__ q, const float* __restrict__ k,
    const float* __restrict__ v, u16* __restrict__ A3)
{
    __shared__ __align__(16) float RING[18 * 1024];   // 72 KB -> 2 blocks/CU
    const int tid  = threadIdx.x;
    const int bid0 = blockIdx.x;                      // 0..383
    const int bid  = (bid0 & 7) * 48 + (bid0 >> 3);   // XCD chunking (384 = 8*48)
    const int ck   = bid & 31;                        // t-chunk 0..31
    const int b    = (bid >> 5) & 3;
    const int inp  = bid >> 7;
    const int t0   = ck * 8;

    const float* src = (inp == 0) ? q : (inp == 1) ? k : v;
    const char* base = (const char*)(src + (size_t)b * Sc * Dc);  // + row*4096 B
    const int tid16 = tid * 16;
    const int wvoff = (tid & 192) * 16;               // wave-uniform segment base
    char* RB = (char*)RING;

    // prologue: window(t0) rows 8t0-9..8t0 into slots (row mod 18)
    if (t0 == 0) {
        const f32x4 zz = (f32x4){0.f, 0.f, 0.f, 0.f};
        #pragma unroll
        for (int i = 0; i < 9; ++i)                   // rows -9..-1 -> slots 9..17
            *(f32x4*)(RB + (9 + i) * 4096 + tid16) = zz;
        gload_lds16(base + tid16, RB + wvoff);        // row 0 -> slot 0
    } else {
        const int r = 8 * t0 - 9;
        const int s = r % 18;
        #pragma unroll
        for (int i = 0; i < 10; ++i) {
            int si = s + i; if (si >= 18) si -= 18;
            gload_lds16(base + (size_t)(r + i) * 4096 + tid16, RB + si * 4096 + wvoff);
        }
    }

    int s0 = (8 * t0 - 9) % 18; if (s0 < 0) s0 += 18; // slot of row 8t-9

    #pragma unroll 1
    for (int st = 0; st < 8; ++st) {
        const int t = t0 + st;
        if (st < 7) {
            // DMA rows 8t+1..8t+8 (window t+1's new rows) into slots s0+10..s0+17
            const int rn = 8 * t + 1;
            int sn = s0 + 10; if (sn >= 18) sn -= 18;
            #pragma unroll
            for (int i = 0; i < 8; ++i) {
                int si = sn + i; if (si >= 18) si -= 18;
                gload_lds16(base + (size_t)(rn + i) * 4096 + tid16,
                            RB + si * 4096 + wvoff);
            }
            if (st == 0) asm volatile("s_waitcnt vmcnt(8)" ::: "memory");
            else         asm volatile("s_waitcnt vmcnt(11)" ::: "memory");
        } else {
            asm volatile("s_waitcnt vmcnt(3)" ::: "memory");   // drain last window's loads
        }
        __builtin_amdgcn_sched_barrier(0);

        f32x4 rr[10];
        #pragma unroll
        for (int i = 0; i < 10; ++i) {
            int si = s0 + i; if (si >= 18) si -= 18;
            rr[i] = *(const f32x4*)(RB + si * 4096 + tid16);
        }
        f32x4 A0 = ((rr[0] + rr[1]) + (rr[2] + rr[3])) + ((rr[4] + rr[5]) + (rr[6] + rr[7]));
        f32x4 B1 = rr[8] - rr[0];
        f32x4 B2 = rr[9] - rr[1];

        size_t so = (size_t)inp * 3145728 + (size_t)(b * 256 + t) * 3072 + tid * 4;
        *(uint2*)(A3 + so)        = pack4v(A0);
        *(uint2*)(A3 + so + 1024) = pack4v(B1);
        *(uint2*)(A3 + so + 2048) = pack4v(B2);

        s0 += 8; if (s0 >= 18) s0 -= 18;
    }
}

// ====== launch 3: fused QKV GEMM + V^T pad, [1024 x 3072] @ Wt3_z^T + biasT ======
__global__ __launch_bounds__(64) void gemm_qkv(
    const u16* __restrict__ A3, const u16* __restrict__ Wt3,
    const float* __restrict__ biasT,
    u16* __restrict__ qb, u16* __restrict__ kb, u16* __restrict__ vt)
{
    __shared__ __align__(16) u16 S[2][2][4096];   // [buf][A|B][64*64]

    const int lane = threadIdx.x;
    const int bid = blockIdx.x;

    if (bid >= 768) {
        // ---- vpad: 4 bh per block ----
        const int vb = bid - 768;                 // 0..15
        #pragma unroll
        for (int bh4 = 0; bh4 < 4; ++bh4) {
            const int bh = vb * 4 + bh4;
            #pragma unroll
            for (int it = 0; it < 8; ++it) {
                int gidx = it * 64 + lane;        // 512 uint4 per bh
                int row  = 64 + (gidx >> 5);
                int c0   = (gidx & 31) * 8;
                u32 fill = (row == 64) ? 0x3F803F80u : 0u;
                *(uint4*)(vt + (size_t)bh * 20480 + (size_t)row * 256 + c0) =
                    make_uint4(fill, fill, fill, fill);
            }
        }
        return;
    }

    const int mi   = lane & 15;
    const int quad = lane >> 4;

    const int wg  = (bid & 7) * 96 + (bid >> 3);  // bijective XCD chunking (768 = 8*96)
    const int z   = wg >> 8;
    const int m0  = ((wg >> 4) & 15) * 64;
    const int n0  = (wg & 15) * 64;

    const char* Ab = (const char*)(A3  + (size_t)z * 3145728) + (size_t)m0 * 6144;
    const char* Bb = (const char*)(Wt3 + (size_t)z * 3145728) + (size_t)n0 * 6144;

    f32x4 acc[4][4];
    #pragma unroll
    for (int i = 0; i < 4; ++i)
        #pragma unroll
        for (int j = 0; j < 4; ++j)
            acc[i][j] = (f32x4){0.f, 0.f, 0.f, 0.f};

    stage64(Ab, 0, S[0][0], lane, 6144);
    stage64(Bb, 0, S[0][1], lane, 6144);

    #pragma unroll 1
    for (int t = 0; t < 48; ++t) {
        const int cur = t & 1;
        if (t < 47) {
            stage64(Ab, (size_t)(t + 1) * 128, S[cur ^ 1][0], lane, 6144);
            stage64(Bb, (size_t)(t + 1) * 128, S[cur ^ 1][1], lane, 6144);
            asm volatile("s_waitcnt vmcnt(16)" ::: "memory");   // cur's 16 done, next 16 in flight
        } else {
            asm volatile("s_waitcnt vmcnt(0)" ::: "memory");
        }
        __builtin_amdgcn_sched_barrier(0);

        bf16x8 af[4][2], bf[4][2];
        frag_read(S[cur][0], mi, quad, af);
        frag_read(S[cur][1], mi, quad, bf);

        #pragma unroll
        for (int kc = 0; kc < 2; ++kc)
            #pragma unroll
            for (int i = 0; i < 4; ++i)
                #pragma unroll
                for (int j = 0; j < 4; ++j)
                    acc[i][j] = __builtin_amdgcn_mfma_f32_16x16x32_bf16(af[i][kc], bf[j][kc], acc[i][j], 0, 0, 0);
    }

    const float* bT = biasT + (size_t)z * 3072;
    if (z == 2) {
        #pragma unroll
        for (int j = 0; j < 4; ++j) {
            const int col = n0 + j * 16 + mi;
            const int h = col >> 6, d = col & 63;
            #pragma unroll
            for (int i = 0; i < 4; ++i) {
                const int row = m0 + i * 16 + quad * 4;
                const int b = row >> 8, t0 = row & 255;
                const int bh = b * 16 + h;
                u16 w[4];
                #pragma unroll
                for (int r = 0; r < 4; ++r) {
                    int t = t0 + r;
                    w[r] = f2bf(acc[i][j][r] + bT[(t < 2 ? t : 2) * 1024 + col]);
                }
                *(uint2*)(vt + (size_t)bh * 20480 + (size_t)d * 256 + t0) =
                    make_uint2((u32)w[0] | ((u32)w[1] << 16), (u32)w[2] | ((u32)w[3] << 16));
            }
        }
    } else {
        u16* dst = z ? kb : qb;
        #pragma unroll
        for (int j = 0; j < 4; ++j) {
            const int col = n0 + j * 16 + mi;
            const int h = col >> 6, d = col & 63;
            #pragma unroll
            for (int i = 0; i < 4; ++i) {
                const int row = m0 + i * 16 + quad * 4;
                const int b = row >> 8;
                const int bh = b * 16 + h;
                #pragma unroll
                for (int r = 0; r < 4; ++r) {
                    int t = (row & 255) + r;
                    dst[(((size_t)bh * 256 + t) << 6) + d] =
                        f2bf(acc[i][j][r] + bT[(t < 2 ? t : 2) * 1024 + col]);
                }
            }
        }
    }
}

// ---------------- launch 4: MFMA causal attention + fused up-dense ----------------
__global__ __launch_bounds__(64) void attn_mfma(
    const u16* __restrict__ qb, const u16* __restrict__ kb,
    const u16* __restrict__ vt, const u16* __restrict__ WupT,
    const float* __restrict__ bup, u16* __restrict__ ms)
{
    __shared__ __align__(16) u16 P[64 * 72];    // stride 72 u16: 2-way banks only
    const int qt   = blockIdx.x;
    const int bh   = blockIdx.y;
    const int lane = threadIdx.x;
    const int mi   = lane & 15;
    const int quad = lane >> 4;

    const u16* Qb = qb + (((size_t)bh * 256 + qt * 64) << 6);
    const u16* Kb = kb + ((size_t)bh << 14);        // *256*64
    const u16* Vt = vt + (size_t)bh * 80 * 256;

    bf16x8 qf[4][2];
    #pragma unroll
    for (int it = 0; it < 4; ++it)
        #pragma unroll
        for (int kc = 0; kc < 2; ++kc)
            qf[it][kc] = *(const bf16x8*)(Qb + ((it * 16 + mi) << 6) + kc * 32 + quad * 8);

    f32x4 o[4][5];
    #pragma unroll
    for (int it = 0; it < 4; ++it)
        #pragma unroll
        for (int jn = 0; jn < 5; ++jn)
            o[it][jn] = (f32x4){0.f, 0.f, 0.f, 0.f};

    for (int kt = 0; kt <= qt; ++kt) {
        bf16x8 kf[4][2];
        #pragma unroll
        for (int jt = 0; jt < 4; ++jt)
            #pragma unroll
            for (int kc = 0; kc < 2; ++kc)
                kf[jt][kc] = *(const bf16x8*)(Kb + ((kt * 64 + jt * 16 + mi) << 6) + kc * 32 + quad * 8);

        f32x4 s[4][4];
        #pragma unroll
        for (int it = 0; it < 4; ++it)
            #pragma unroll
            for (int jt = 0; jt < 4; ++jt)
                s[it][jt] = (f32x4){0.f, 0.f, 0.f, 0.f};
        #pragma unroll
        for (int kc = 0; kc < 2; ++kc)
            #pragma unroll
            for (int it = 0; it < 4; ++it)
                #pragma unroll
                for (int jt = 0; jt < 4; ++jt)
                    s[it][jt] = __builtin_amdgcn_mfma_f32_16x16x32_bf16(qf[it][kc], kf[jt][kc], s[it][jt], 0, 0, 0);

        const bool diag = (kt == qt);
        #pragma unroll
        for (int it = 0; it < 4; ++it)
            #pragma unroll
            for (int jt = 0; jt < 4; ++jt)
                #pragma unroll
                for (int r = 0; r < 4; ++r) {
                    int qrow = it * 16 + quad * 4 + r;
                    int kcol = jt * 16 + mi;
                    float e = __expf(s[it][jt][r]);
                    if (diag && kcol > qrow) e = 0.f;
                    P[qrow * 72 + kcol] = f2bf(e);
                }

        bf16x8 pf[4][2];
        #pragma unroll
        for (int it = 0; it < 4; ++it)
            #pragma unroll
            for (int kc = 0; kc < 2; ++kc)
                pf[it][kc] = *(const bf16x8*)(P + (it * 16 + mi) * 72 + kc * 32 + quad * 8);

        bf16x8 vf[5][2];
        #pragma unroll
        for (int jn = 0; jn < 5; ++jn)
            #pragma unroll
            for (int kc = 0; kc < 2; ++kc)
                vf[jn][kc] = *(const bf16x8*)(Vt + (size_t)(jn * 16 + mi) * 256 + kt * 64 + kc * 32 + quad * 8);

        #pragma unroll
        for (int kc = 0; kc < 2; ++kc)
            #pragma unroll
            for (int it = 0; it < 4; ++it)
                #pragma unroll
                for (int jn = 0; jn < 5; ++jn)
                    o[it][jn] = __builtin_amdgcn_mfma_f32_16x16x32_bf16(pf[it][kc], vf[jn][kc], o[it][jn], 0, 0, 0);
    }

    // epilogue A: normalize -> G bf16 in P
    #pragma unroll
    for (int it = 0; it < 4; ++it) {
        float inv[4];
        #pragma unroll
        for (int r = 0; r < 4; ++r) {
            float lv = __shfl(o[it][4][r], (lane & 48));   // from lane quad*16+0
            inv[r] = 1.0f / lv;
        }
        #pragma unroll
        for (int jn = 0; jn < 4; ++jn)
            #pragma unroll
            for (int r = 0; r < 4; ++r) {
                int row = it * 16 + quad * 4 + r;
                P[row * 72 + jn * 16 + mi] = f2bf(o[it][jn][r] * inv[r]);
            }
    }

    // epilogue B: up-dense R = G @ Wup via MFMA
    bf16x8 ga[4][2], wf[4][2];
    #pragma unroll
    for (int it = 0; it < 4; ++it)
        #pragma unroll
        for (int kc = 0; kc < 2; ++kc)
            ga[it][kc] = *(const bf16x8*)(P + (it * 16 + mi) * 72 + kc * 32 + quad * 8);
    #pragma unroll
    for (int jn = 0; jn < 4; ++jn)
        #pragma unroll
        for (int kc = 0; kc < 2; ++kc)
            wf[jn][kc] = *(const bf16x8*)(WupT + (jn * 16 + mi) * 64 + kc * 32 + quad * 8);

    f32x4 u[4][4];
    #pragma unroll
    for (int it = 0; it < 4; ++it)
        #pragma unroll
        for (int jn = 0; jn < 4; ++jn)
            u[it][jn] = (f32x4){0.f, 0.f, 0.f, 0.f};
    #pragma unroll
    for (int kc = 0; kc < 2; ++kc)
        #pragma unroll
        for (int it = 0; it < 4; ++it)
            #pragma unroll
            for (int jn = 0; jn < 4; ++jn)
                u[it][jn] = __builtin_amdgcn_mfma_f32_16x16x32_bf16(ga[it][kc], wf[jn][kc], u[it][jn], 0, 0, 0);

    const int b = bh >> 4, h = bh & 15;
    #pragma unroll
    for (int jn = 0; jn < 4; ++jn) {
        const int dp = jn * 16 + mi;
        const float bv = bup[dp];
        #pragma unroll
        for (int it = 0; it < 4; ++it)
            #pragma unroll
            for (int r = 0; r < 4; ++r) {
                int m = qt * 64 + it * 16 + quad * 4 + r;
                ms[((size_t)(b * 256 + m) << 10) + h * 64 + dp] = f2bf(u[it][jn][r] + bv);
            }
    }
}

// ====== launch 5: final dense + fused 8x upsample, straight into d_out ======
__global__ __launch_bounds__(64) void gemm_out_up(
    const u16* __restrict__ A, const u16* __restrict__ Bt,
    const float* __restrict__ bias, float* __restrict__ out)
{
    __shared__ __align__(16) u16 S[2][2][4096];
    __shared__ __align__(16) float Cs[64][68];    // pad 68: 16B-aligned rows

    const int lane = threadIdx.x;
    const int mi   = lane & 15;
    const int quad = lane >> 4;

    const int bid = blockIdx.x;                   // 0..255
    const int wg  = (bid & 7) * 32 + (bid >> 3);  // bijective XCD chunking (256 = 8*32)
    const int m0  = (wg >> 4) * 64;
    const int n0  = (wg & 15) * 64;

    const char* Ab = (const char*)A  + (size_t)m0 * 2048;
    const char* Bb = (const char*)Bt + (size_t)n0 * 2048;

    f32x4 acc[4][4];
    #pragma unroll
    for (int i = 0; i < 4; ++i)
        #pragma unroll
        for (int j = 0; j < 4; ++j)
            acc[i][j] = (f32x4){0.f, 0.f, 0.f, 0.f};

    stage64(Ab, 0, S[0][0], lane, 2048);
    stage64(Bb, 0, S[0][1], lane, 2048);

    #pragma unroll 1
    for (int t = 0; t < 16; ++t) {
        const int cur = t & 1;
        if (t < 15) {
            stage64(Ab, (size_t)(t + 1) * 128, S[cur ^ 1][0], lane, 2048);
            stage64(Bb, (size_t)(t + 1) * 128, S[cur ^ 1][1], lane, 2048);
            asm volatile("s_waitcnt vmcnt(16)" ::: "memory");
        } else {
            asm volatile("s_waitcnt vmcnt(0)" ::: "memory");
        }
        __builtin_amdgcn_sched_barrier(0);

        bf16x8 af[4][2], bf[4][2];
        frag_read(S[cur][0], mi, quad, af);
        frag_read(S[cur][1], mi, quad, bf);

        #pragma unroll
        for (int kc = 0; kc < 2; ++kc)
            #pragma unroll
            for (int i = 0; i < 4; ++i)
                #pragma unroll
                for (int j = 0; j < 4; ++j)
                    acc[i][j] = __builtin_amdgcn_mfma_f32_16x16x32_bf16(af[i][kc], bf[j][kc], acc[i][j], 0, 0, 0);
    }

    #pragma unroll
    for (int j = 0; j < 4; ++j) {
        const float bv = bias[n0 + j * 16 + mi];
        #pragma unroll
        for (int i = 0; i < 4; ++i)
            #pragma unroll
            for (int r = 0; r < 4; ++r)
                Cs[i * 16 + quad * 4 + r][j * 16 + mi] = acc[i][j][r] + bv;
    }

    const int col4 = lane & 15;
    #pragma unroll 4
    for (int it = 0; it < 128; ++it) {
        const int crow = it >> 1;
        const int rep  = ((it & 1) << 2) + (lane >> 4);
        float4 val = *(const float4*)&Cs[crow][col4 * 4];
        const int R = m0 + crow;
        const int b = R >> 8, tc = R & 255;
        float* po = out + (((size_t)((b << 11) + (tc << 3) + rep)) << 10) + n0 + (col4 << 2);
        *(float4*)po = val;
    }
}

extern "C" void kernel_launch(void* const* d_in, const int* in_sizes, int n_in,
                              void* d_out, int out_size, void* d_ws, size_t ws_size,
                              hipStream_t stream) {
    const float* q   = (const float*)d_in[0];
    const float* k   = (const float*)d_in[1];
    const float* v   = (const float*)d_in[2];
    const float* Wq  = (const float*)d_in[3];
    const float* bq  = (const float*)d_in[4];
    const float* Wk  = (const float*)d_in[5];
    const float* bk  = (const float*)d_in[6];
    const float* Wv  = (const float*)d_in[7];
    const float* bv  = (const float*)d_in[8];
    const float* Wup = (const float*)d_in[9];
    const float* bup = (const float*)d_in[10];
    const float* Wc  = (const float*)d_in[11];
    const float* bc  = (const float*)d_in[12];
    const float* wcq = (const float*)d_in[13];
    const float* bcq = (const float*)d_in[14];
    const float* wck = (const float*)d_in[15];
    const float* bck = (const float*)d_in[16];
    const float* wcv = (const float*)d_in[17];
    const float* bcv = (const float*)d_in[18];

    // A3 staging (18.9 MB bf16 [3][1024][3072]) lives in d_out; gemm_out_up
    // rewrites all of d_out at the end.
    u16* A3 = (u16*)d_out;

    char* wsb = (char*)d_ws;
    // ws layout (bytes):
    //   0        : Wt3  bf16 [3][1024 n][3072 k]  18,874,368
    //   18874368 : Wtc  bf16 [1024][1024]          2,097,152
    //   20971520 : biasT f32 [3][3][1024]             36,864
    //   21008384 : qb   bf16 [64*256][64]          2,097,152
    //   23105536 : kb   bf16 [64*256][64]          2,097,152
    //   25202688 : vt   bf16 [64][80][256]         2,621,440
    //   27824128 : WupT bf16 [64][64]                  8,192
    //   32018432 : ms   bf16 [1024][1024]          2,097,152
    u16*   Wt3   = (u16*)wsb;
    u16*   Wtc   = (u16*)(wsb + 18874368);
    float* biasT = (float*)(wsb + 20971520);
    u16*   qb    = (u16*)(wsb + 21008384);
    u16*   kb    = (u16*)(wsb + 23105536);
    u16*   vt    = (u16*)(wsb + 25202688);
    u16*   WupT  = (u16*)(wsb + 27824128);
    u16*   ms    = (u16*)(wsb + 32018432);

    // 1. weight prep + bias table + WupT (high-occupancy, 16.9KB LDS)
    prep_misc<<<1037, 256, 0, stream>>>(Wq, Wk, Wv, Wc, Wup,
                                        wcq, wck, wcv, bcq, bck, bcv,
                                        bq, bk, bv, Wt3, Wtc, biasT, WupT);
    // 2. sliding-window staging (384 blocks, 72KB ring, counted-vmcnt pipeline)
    stage_slide<<<384, 256, 0, stream>>>(q, k, v, A3);
    // 3. fused QKV GEMM + V^T pad (784 one-wave blocks)
    gemm_qkv<<<784, 64, 0, stream>>>(A3, Wt3, biasT, qb, kb, vt);
    // 4. MFMA causal attention + fused up-dense -> ms (256 one-wave blocks)
    attn_mfma<<<dim3(4, 64), 64, 0, stream>>>(qb, kb, vt, WupT, bup, ms);
    // 5. final dense + fused 8x upsample -> d_out (256 one-wave blocks)
    gemm_out_up<<<256, 64, 0, stream>>>(ms, Wtc, bc, (float*)d_out);
}

// Round 11
// 241.530 us; speedup vs baseline: 1.0094x; 1.0094x over previous
//
#include <hip/hip_runtime.h>
#include <cstdint>
#include <cstddef>

// Problem constants
#define Bc  4
#define Sc  2048
#define Dc  1024
#define Hc  16
#define DDc 64
#define Nc  256   // pooled length

typedef unsigned short u16;
typedef unsigned int   u32;
typedef __bf16 bf16_t;
typedef bf16_t bf16x8 __attribute__((ext_vector_type(8)));
typedef float  f32x4  __attribute__((ext_vector_type(4)));

__device__ __forceinline__ u16 f2bf(float x) {
    u32 u = __float_as_uint(x);
    return (u16)((u + 0x7FFFu + ((u >> 16) & 1u)) >> 16);   // RNE
}
__device__ __forceinline__ u32 pack2(float a, float b) {
    return (u32)f2bf(a) | ((u32)f2bf(b) << 16);
}
__device__ __forceinline__ uint2 pack4v(f32x4 x) {
    return make_uint2(pack2(x[0], x[1]), pack2(x[2], x[3]));
}
__device__ __forceinline__ float bf2f(u16 x) {
    return __uint_as_float((u32)x << 16);
}

// async global->LDS, 16B per lane (global src per-lane; LDS dest = wave-uniform base + lane*16)
__device__ __forceinline__ void gload_lds16(const void* gp, void* lp) {
    __builtin_amdgcn_global_load_lds(
        reinterpret_cast<const __attribute__((address_space(1))) void*>(
            reinterpret_cast<uintptr_t>(gp)),
        reinterpret_cast<__attribute__((address_space(3))) void*>(
            reinterpret_cast<uintptr_t>(lp)),
        16, 0, 0);
}

// ---- 1-wave GEMM building blocks (64x64 tile, BK=64, granule-swizzled LDS) ----
__device__ __forceinline__ void stage64(const char* src, size_t kb, u16* lds,
                                        int lane, size_t rstride) {
    const int rowoff = lane >> 3;                       // 0..7
    const int srcg   = ((lane & 7) ^ (rowoff & 7)) * 16;
    const char* s0 = src + kb + (size_t)srcg;
    #pragma unroll
    for (int i = 0; i < 8; ++i)
        gload_lds16(s0 + (size_t)(8 * i + rowoff) * rstride,
                    (char*)lds + i * 1024);             // wave-uniform dest base
}

__device__ __forceinline__ void frag_read(const u16* lds, int mi, int quad,
                                          bf16x8 f[4][2]) {
    const int key = mi & 7;                             // (i*16+mi)&7 == mi&7
    #pragma unroll
    for (int i = 0; i < 4; ++i)
        #pragma unroll
        for (int kc = 0; kc < 2; ++kc) {
            int g = (kc * 4 + quad) ^ key;
            f[i][kc] = *(const bf16x8*)(lds + (i * 16 + mi) * 64 + g * 8);
        }
}

// ================= launch 1: prep + bias + WupT + stage, one dispatch =================
// blocks [0,1024)    : weight prep (z = bid>>8, k0 = ((bid>>4)&15)*64, n0 = (bid&15)*64)
// blocks [1024,1036) : bias table
// block  1036        : Wup transpose -> WupT bf16 [dp][d]
// blocks [1037,4109) : input staging -- one block per (inp,b,t), 10 rows via
//                      global_load_lds into 40KB LDS. (Stage is at its pattern
//                      wall ~2.2 TB/s: register/DMA/pipelined-ring variants all
//                      measured 43-47us, r8-r10. Do not re-attack.)
__global__ __launch_bounds__(256) void prep_stage(
    const float* __restrict__ q,  const float* __restrict__ k,  const float* __restrict__ v,
    const float* __restrict__ Wq, const float* __restrict__ Wk,
    const float* __restrict__ Wv, const float* __restrict__ Wc,
    const float* __restrict__ Wup,
    const float* __restrict__ wcq, const float* __restrict__ wck, const float* __restrict__ wcv,
    const float* __restrict__ bcq, const float* __restrict__ bck, const float* __restrict__ bcv,
    const float* __restrict__ bq,  const float* __restrict__ bk,  const float* __restrict__ bv,
    u16* __restrict__ Wt3, u16* __restrict__ Wtc, float* __restrict__ biasT,
    u16* __restrict__ WupT, u16* __restrict__ A3)
{
    __shared__ __align__(16) float LS[10 * 1024];   // 40KB: rows[10][1024] / T[64][65]
    float (*T)[65] = (float(*)[65])LS;
    const int bid = blockIdx.x;
    const int tid = threadIdx.x;

    if (bid < 1024) {
        // ---------------- weight prep ----------------
        const int z = bid >> 8;
        const float* W = (z == 0) ? Wq : (z == 1) ? Wk : (z == 2) ? Wv : Wc;
        const int k0 = ((bid >> 4) & 15) * 64, n0 = (bid & 15) * 64;
        const int c = tid & 63, r4 = tid >> 6;
        #pragma unroll
        for (int i = 0; i < 16; ++i) {
            int r = i * 4 + r4;
            T[r][c] = W[(size_t)(k0 + r) * 1024 + n0 + c];
        }
        __syncthreads();
        if (z < 3) {
            const float* wc = (z == 0) ? wcq : (z == 1) ? wck : wcv;
            const float fs = 0.125f * ((z == 2) ? 1.0f : 0.35355339059327373f);
            u16* dst0 = Wt3 + (size_t)z * 3145728;
            #pragma unroll
            for (int i = 0; i < 16; ++i) {
                int r = i * 4 + r4;
                int n = n0 + r;
                float w0 = wc[n], w1 = wc[1024 + n], w2 = wc[2048 + n];
                float s2 = fs * w2, s1 = s2 + fs * w1, s0 = s1 + fs * w0;
                float x = T[c][r];
                u16* dst = dst0 + (size_t)n * 3072 + k0 + c;
                dst[0]    = f2bf(x * s0);
                dst[1024] = f2bf(x * s1);
                dst[2048] = f2bf(x * s2);
            }
        } else {
            #pragma unroll
            for (int i = 0; i < 16; ++i) {
                int r = i * 4 + r4;
                Wtc[(size_t)(n0 + r) * 1024 + k0 + c] = f2bf(T[c][r]);
            }
        }
        return;
    }

    if (bid < 1036) {
        // ---------------- bias table: biasT[z][j][c], j = min(t,2) ----------------
        int gid = (bid - 1024) * 256 + tid;   // over 3*1024
        int c = gid & 1023, z = gid >> 10;
        const float* wc    = (z == 0) ? wcq : (z == 1) ? wck : wcv;
        const float* bconv = (z == 0) ? bcq : (z == 1) ? bck : bcv;
        const float* bl    = (z == 0) ? bq  : (z == 1) ? bk  : bv;
        const float nrm = (z == 2) ? 1.0f : 0.35355339059327373f;
        float w0 = wc[c], w1 = wc[1024 + c], w2 = wc[2048 + c];
        float bc_ = bconv[c], bl_ = bl[c];
        float* dst = biasT + (size_t)z * 3072 + c;
        dst[0]    = 0.125f * (bc_ + nrm * bl_ * w2);
        dst[1024] = 0.125f * (8.f * bc_ + nrm * bl_ * (7.f * w0 + 8.f * w1 + 8.f * w2));
        dst[2048] = 0.125f * (8.f * bc_ + nrm * bl_ * 8.f * (w0 + w1 + w2));
        return;
    }

    if (bid == 1036) {
        // ---------------- Wup transpose: WupT[dp][d] = Wup[d][dp], bf16 ----------------
        const int c = tid & 63, r4 = tid >> 6;
        #pragma unroll
        for (int i = 0; i < 16; ++i) {
            int r = i * 4 + r4;
            T[r][c] = Wup[r * 64 + c];
        }
        __syncthreads();
        #pragma unroll
        for (int i = 0; i < 16; ++i) {
            int r = i * 4 + r4;
            WupT[r * 64 + c] = f2bf(T[c][r]);
        }
        return;
    }

    // ---------------- staging: one block per (inp,b,t), all 1024 channels ----------------
    //   A0[t] = sum rows 8t-9..8t-2 ; B1[t] = x[8t-1]-x[8t-9] ; B2[t] = x[8t]-x[8t-8]
    int sbid0 = bid - 1037;                             // 0..3071
    int sbid  = (sbid0 & 7) * 384 + (sbid0 >> 3);       // bijective XCD chunk (3072=8*384)
    int t = sbid & 255, b = (sbid >> 8) & 3, inp = sbid >> 10;
    const float* src = (inp == 0) ? q : (inp == 1) ? k : v;
    const char* base = (const char*)(src + (size_t)b * Sc * Dc);   // + row*4096 bytes
    const int tid16 = tid * 16;
    const int wvoff = (tid & 192) * 16;                 // wave-uniform segment base
    char* LSB = (char*)LS;

    const int nneg = (t >= 2) ? 0 : (t == 1 ? 1 : 9);   // missing (negative) rows
    const f32x4 zz = (f32x4){0.f, 0.f, 0.f, 0.f};
    for (int i = 0; i < nneg; ++i)                      // zero-fill missing rows
        *(f32x4*)(LSB + i * 4096 + tid16) = zz;
    #pragma unroll
    for (int i = 0; i < 10; ++i)                        // async DMA the valid rows
        if (i >= nneg)
            gload_lds16(base + (size_t)(8 * t - 9 + i) * 4096 + tid16,
                        LSB + i * 4096 + wvoff);
    __syncthreads();                                    // drains vmcnt + lgkmcnt

    f32x4 rr[10];
    #pragma unroll
    for (int i = 0; i < 10; ++i)
        rr[i] = *(const f32x4*)(LSB + i * 4096 + tid16);

    f32x4 A0 = ((rr[0] + rr[1]) + (rr[2] + rr[3])) + ((rr[4] + rr[5]) + (rr[6] + rr[7]));
    f32x4 B1 = rr[8] - rr[0];
    f32x4 B2 = rr[9] - rr[1];

    size_t s0 = (size_t)inp * 3145728 + (size_t)(b * 256 + t) * 3072 + tid * 4;
    *(uint2*)(A3 + s0)        = pack4v(A0);
    *(uint2*)(A3 + s0 + 1024) = pack4v(B1);
    *(uint2*)(A3 + s0 + 2048) = pack4v(B2);
}

// ====== launch 2: fused QKV GEMM + V^T pad, [1024 x 3072] @ Wt3_z^T + biasT ======
// blocks [0,768): 1-wave 64x64-tile GEMM (counted-vmcnt double-buffer).
// n-band XCD mapping: XCD x (= bid&7) owns n in {2x, 2x+1} for ALL (z,m) ->
// per-XCD B working set = 2 cols x 3 z x 384KB = 2.25MB, L2-resident for the
// whole kernel; A-panels read in adjacent n-pairs (2nd is L2 hit). Cuts L3
// traffic ~590 -> ~170MB (r10: 64x64 tiles were L3-BW-bound, MfmaUtil 16%).
// blocks [768,784): V^T pad rows 64..79 (row 64 = 1.0 softmax-l trick, rest 0)
__global__ __launch_bounds__(64) void gemm_qkv(
    const u16* __restrict__ A3, const u16* __restrict__ Wt3,
    const float* __restrict__ biasT,
    u16* __restrict__ qb, u16* __restrict__ kb, u16* __restrict__ vt)
{
    __shared__ __align__(16) u16 S[2][2][4096];   // [buf][A|B][64*64]

    const int lane = threadIdx.x;
    const int bid = blockIdx.x;

    if (bid >= 768) {
        // ---- vpad: 4 bh per block ----
        const int vb = bid - 768;                 // 0..15
        #pragma unroll
        for (int bh4 = 0; bh4 < 4; ++bh4) {
            const int bh = vb * 4 + bh4;
            #pragma unroll
            for (int it = 0; it < 8; ++it) {
                int gidx = it * 64 + lane;        // 512 uint4 per bh
                int row  = 64 + (gidx >> 5);
                int c0   = (gidx & 31) * 8;
                u32 fill = (row == 64) ? 0x3F803F80u : 0u;
                *(uint4*)(vt + (size_t)bh * 20480 + (size_t)row * 256 + c0) =
                    make_uint4(fill, fill, fill, fill);
            }
        }
        return;
    }

    const int mi   = lane & 15;
    const int quad = lane >> 4;

    // n-band XCD mapping (bijective): xcd = bid&7, i = bid>>3 in [0,96)
    //   z = i>>5, m = (i>>1)&15, n = xcd*2 + (i&1)
    const int xcd = bid & 7;
    const int i_  = bid >> 3;
    const int z   = i_ >> 5;
    const int m0  = ((i_ >> 1) & 15) * 64;
    const int n0  = (xcd * 2 + (i_ & 1)) * 64;

    const char* Ab = (const char*)(A3  + (size_t)z * 3145728) + (size_t)m0 * 6144;
    const char* Bb = (const char*)(Wt3 + (size_t)z * 3145728) + (size_t)n0 * 6144;

    f32x4 acc[4][4];
    #pragma unroll
    for (int i = 0; i < 4; ++i)
        #pragma unroll
        for (int j = 0; j < 4; ++j)
            acc[i][j] = (f32x4){0.f, 0.f, 0.f, 0.f};

    stage64(Ab, 0, S[0][0], lane, 6144);
    stage64(Bb, 0, S[0][1], lane, 6144);

    #pragma unroll 1
    for (int t = 0; t < 48; ++t) {
        const int cur = t & 1;
        if (t < 47) {
            stage64(Ab, (size_t)(t + 1) * 128, S[cur ^ 1][0], lane, 6144);
            stage64(Bb, (size_t)(t + 1) * 128, S[cur ^ 1][1], lane, 6144);
            asm volatile("s_waitcnt vmcnt(16)" ::: "memory");   // cur's 16 done, next 16 in flight
        } else {
            asm volatile("s_waitcnt vmcnt(0)" ::: "memory");
        }
        __builtin_amdgcn_sched_barrier(0);

        bf16x8 af[4][2], bf[4][2];
        frag_read(S[cur][0], mi, quad, af);
        frag_read(S[cur][1], mi, quad, bf);

        #pragma unroll
        for (int kc = 0; kc < 2; ++kc)
            #pragma unroll
            for (int i = 0; i < 4; ++i)
                #pragma unroll
                for (int j = 0; j < 4; ++j)
                    acc[i][j] = __builtin_amdgcn_mfma_f32_16x16x32_bf16(af[i][kc], bf[j][kc], acc[i][j], 0, 0, 0);
    }

    const float* bT = biasT + (size_t)z * 3072;
    if (z == 2) {
        #pragma unroll
        for (int j = 0; j < 4; ++j) {
            const int col = n0 + j * 16 + mi;
            const int h = col >> 6, d = col & 63;
            #pragma unroll
            for (int i = 0; i < 4; ++i) {
                const int row = m0 + i * 16 + quad * 4;
                const int b = row >> 8, t0 = row & 255;
                const int bh = b * 16 + h;
                u16 w[4];
                #pragma unroll
                for (int r = 0; r < 4; ++r) {
                    int t = t0 + r;
                    w[r] = f2bf(acc[i][j][r] + bT[(t < 2 ? t : 2) * 1024 + col]);
                }
                *(uint2*)(vt + (size_t)bh * 20480 + (size_t)d * 256 + t0) =
                    make_uint2((u32)w[0] | ((u32)w[1] << 16), (u32)w[2] | ((u32)w[3] << 16));
            }
        }
    } else {
        u16* dst = z ? kb : qb;
        #pragma unroll
        for (int j = 0; j < 4; ++j) {
            const int col = n0 + j * 16 + mi;
            const int h = col >> 6, d = col & 63;
            #pragma unroll
            for (int i = 0; i < 4; ++i) {
                const int row = m0 + i * 16 + quad * 4;
                const int b = row >> 8;
                const int bh = b * 16 + h;
                #pragma unroll
                for (int r = 0; r < 4; ++r) {
                    int t = (row & 255) + r;
                    dst[(((size_t)bh * 256 + t) << 6) + d] =
                        f2bf(acc[i][j][r] + bT[(t < 2 ? t : 2) * 1024 + col]);
                }
            }
        }
    }
}

// ---------------- launch 3: MFMA causal attention + fused up-dense ----------------
__global__ __launch_bounds__(64) void attn_mfma(
    const u16* __restrict__ qb, const u16* __restrict__ kb,
    const u16* __restrict__ vt, const u16* __restrict__ WupT,
    const float* __restrict__ bup, u16* __restrict__ ms)
{
    __shared__ __align__(16) u16 P[64 * 72];    // stride 72 u16: 2-way banks only
    const int qt   = blockIdx.x;
    const int bh   = blockIdx.y;
    const int lane = threadIdx.x;
    const int mi   = lane & 15;
    const int quad = lane >> 4;

    const u16* Qb = qb + (((size_t)bh * 256 + qt * 64) << 6);
    const u16* Kb = kb + ((size_t)bh << 14);        // *256*64
    const u16* Vt = vt + (size_t)bh * 80 * 256;

    bf16x8 qf[4][2];
    #pragma unroll
    for (int it = 0; it < 4; ++it)
        #pragma unroll
        for (int kc = 0; kc < 2; ++kc)
            qf[it][kc] = *(const bf16x8*)(Qb + ((it * 16 + mi) << 6) + kc * 32 + quad * 8);

    f32x4 o[4][5];
    #pragma unroll
    for (int it = 0; it < 4; ++it)
        #pragma unroll
        for (int jn = 0; jn < 5; ++jn)
            o[it][jn] = (f32x4){0.f, 0.f, 0.f, 0.f};

    for (int kt = 0; kt <= qt; ++kt) {
        bf16x8 kf[4][2];
        #pragma unroll
        for (int jt = 0; jt < 4; ++jt)
            #pragma unroll
            for (int kc = 0; kc < 2; ++kc)
                kf[jt][kc] = *(const bf16x8*)(Kb + ((kt * 64 + jt * 16 + mi) << 6) + kc * 32 + quad * 8);

        f32x4 s[4][4];
        #pragma unroll
        for (int it = 0; it < 4; ++it)
            #pragma unroll
            for (int jt = 0; jt < 4; ++jt)
                s[it][jt] = (f32x4){0.f, 0.f, 0.f, 0.f};
        #pragma unroll
        for (int kc = 0; kc < 2; ++kc)
            #pragma unroll
            for (int it = 0; it < 4; ++it)
                #pragma unroll
                for (int jt = 0; jt < 4; ++jt)
                    s[it][jt] = __builtin_amdgcn_mfma_f32_16x16x32_bf16(qf[it][kc], kf[jt][kc], s[it][jt], 0, 0, 0);

        const bool diag = (kt == qt);
        #pragma unroll
        for (int it = 0; it < 4; ++it)
            #pragma unroll
            for (int jt = 0; jt < 4; ++jt)
                #pragma unroll
                for (int r = 0; r < 4; ++r) {
                    int qrow = it * 16 + quad * 4 + r;
                    int kcol = jt * 16 + mi;
                    float e = __expf(s[it][jt][r]);
                    if (diag && kcol > qrow) e = 0.f;
                    P[qrow * 72 + kcol] = f2bf(e);
                }

        bf16x8 pf[4][2];
        #pragma unroll
        for (int it = 0; it < 4; ++it)
            #pragma unroll
            for (int kc = 0; kc < 2; ++kc)
                pf[it][kc] = *(const bf16x8*)(P + (it * 16 + mi) * 72 + kc * 32 + quad * 8);

        bf16x8 vf[5][2];
        #pragma unroll
        for (int jn = 0; jn < 5; ++jn)
            #pragma unroll
            for (int kc = 0; kc < 2; ++kc)
                vf[jn][kc] = *(const bf16x8*)(Vt + (size_t)(jn * 16 + mi) * 256 + kt * 64 + kc * 32 + quad * 8);

        #pragma unroll
        for (int kc = 0; kc < 2; ++kc)
            #pragma unroll
            for (int it = 0; it < 4; ++it)
                #pragma unroll
                for (int jn = 0; jn < 5; ++jn)
                    o[it][jn] = __builtin_amdgcn_mfma_f32_16x16x32_bf16(pf[it][kc], vf[jn][kc], o[it][jn], 0, 0, 0);
    }

    // epilogue A: normalize -> G bf16 in P
    #pragma unroll
    for (int it = 0; it < 4; ++it) {
        float inv[4];
        #pragma unroll
        for (int r = 0; r < 4; ++r) {
            float lv = __shfl(o[it][4][r], (lane & 48));   // from lane quad*16+0
            inv[r] = 1.0f / lv;
        }
        #pragma unroll
        for (int jn = 0; jn < 4; ++jn)
            #pragma unroll
            for (int r = 0; r < 4; ++r) {
                int row = it * 16 + quad * 4 + r;
                P[row * 72 + jn * 16 + mi] = f2bf(o[it][jn][r] * inv[r]);
            }
    }

    // epilogue B: up-dense R = G @ Wup via MFMA
    bf16x8 ga[4][2], wf[4][2];
    #pragma unroll
    for (int it = 0; it < 4; ++it)
        #pragma unroll
        for (int kc = 0; kc < 2; ++kc)
            ga[it][kc] = *(const bf16x8*)(P + (it * 16 + mi) * 72 + kc * 32 + quad * 8);
    #pragma unroll
    for (int jn = 0; jn < 4; ++jn)
        #pragma unroll
        for (int kc = 0; kc < 2; ++kc)
            wf[jn][kc] = *(const bf16x8*)(WupT + (jn * 16 + mi) * 64 + kc * 32 + quad * 8);

    f32x4 u[4][4];
    #pragma unroll
    for (int it = 0; it < 4; ++it)
        #pragma unroll
        for (int jn = 0; jn < 4; ++jn)
            u[it][jn] = (f32x4){0.f, 0.f, 0.f, 0.f};
    #pragma unroll
    for (int kc = 0; kc < 2; ++kc)
        #pragma unroll
        for (int it = 0; it < 4; ++it)
            #pragma unroll
            for (int jn = 0; jn < 4; ++jn)
                u[it][jn] = __builtin_amdgcn_mfma_f32_16x16x32_bf16(ga[it][kc], wf[jn][kc], u[it][jn], 0, 0, 0);

    const int b = bh >> 4, h = bh & 15;
    #pragma unroll
    for (int jn = 0; jn < 4; ++jn) {
        const int dp = jn * 16 + mi;
        const float bv = bup[dp];
        #pragma unroll
        for (int it = 0; it < 4; ++it)
            #pragma unroll
            for (int r = 0; r < 4; ++r) {
                int m = qt * 64 + it * 16 + quad * 4 + r;
                ms[((size_t)(b * 256 + m) << 10) + h * 64 + dp] = f2bf(u[it][jn][r] + bv);
            }
    }
}

// ====== launch 4: final dense + fused 8x upsample, straight into d_out ======
__global__ __launch_bounds__(64) void gemm_out_up(
    const u16* __restrict__ A, const u16* __restrict__ Bt,
    const float* __restrict__ bias, float* __restrict__ out)
{
    __shared__ __align__(16) u16 S[2][2][4096];
    __shared__ __align__(16) float Cs[64][68];    // pad 68: 16B-aligned rows

    const int lane = threadIdx.x;
    const int mi   = lane & 15;
    const int quad = lane >> 4;

    const int bid = blockIdx.x;                   // 0..255
    const int wg  = (bid & 7) * 32 + (bid >> 3);  // bijective XCD chunking (256 = 8*32)
    const int m0  = (wg >> 4) * 64;
    const int n0  = (wg & 15) * 64;

    const char* Ab = (const char*)A  + (size_t)m0 * 2048;
    const char* Bb = (const char*)Bt + (size_t)n0 * 2048;

    f32x4 acc[4][4];
    #pragma unroll
    for (int i = 0; i < 4; ++i)
        #pragma unroll
        for (int j = 0; j < 4; ++j)
            acc[i][j] = (f32x4){0.f, 0.f, 0.f, 0.f};

    stage64(Ab, 0, S[0][0], lane, 2048);
    stage64(Bb, 0, S[0][1], lane, 2048);

    #pragma unroll 1
    for (int t = 0; t < 16; ++t) {
        const int cur = t & 1;
        if (t < 15) {
            stage64(Ab, (size_t)(t + 1) * 128, S[cur ^ 1][0], lane, 2048);
            stage64(Bb, (size_t)(t + 1) * 128, S[cur ^ 1][1], lane, 2048);
            asm volatile("s_waitcnt vmcnt(16)" ::: "memory");
        } else {
            asm volatile("s_waitcnt vmcnt(0)" ::: "memory");
        }
        __builtin_amdgcn_sched_barrier(0);

        bf16x8 af[4][2], bf[4][2];
        frag_read(S[cur][0], mi, quad, af);
        frag_read(S[cur][1], mi, quad, bf);

        #pragma unroll
        for (int kc = 0; kc < 2; ++kc)
            #pragma unroll
            for (int i = 0; i < 4; ++i)
                #pragma unroll
                for (int j = 0; j < 4; ++j)
                    acc[i][j] = __builtin_amdgcn_mfma_f32_16x16x32_bf16(af[i][kc], bf[j][kc], acc[i][j], 0, 0, 0);
    }

    #pragma unroll
    for (int j = 0; j < 4; ++j) {
        const float bv = bias[n0 + j * 16 + mi];
        #pragma unroll
        for (int i = 0; i < 4; ++i)
            #pragma unroll
            for (int r = 0; r < 4; ++r)
                Cs[i * 16 + quad * 4 + r][j * 16 + mi] = acc[i][j][r] + bv;
    }

    const int col4 = lane & 15;
    #pragma unroll 4
    for (int it = 0; it < 128; ++it) {
        const int crow = it >> 1;
        const int rep  = ((it & 1) << 2) + (lane >> 4);
        float4 val = *(const float4*)&Cs[crow][col4 * 4];
        const int R = m0 + crow;
        const int b = R >> 8, tc = R & 255;
        float* po = out + (((size_t)((b << 11) + (tc << 3) + rep)) << 10) + n0 + (col4 << 2);
        *(float4*)po = val;
    }
}

extern "C" void kernel_launch(void* const* d_in, const int* in_sizes, int n_in,
                              void* d_out, int out_size, void* d_ws, size_t ws_size,
                              hipStream_t stream) {
    const float* q   = (const float*)d_in[0];
    const float* k   = (const float*)d_in[1];
    const float* v   = (const float*)d_in[2];
    const float* Wq  = (const float*)d_in[3];
    const float* bq  = (const float*)d_in[4];
    const float* Wk  = (const float*)d_in[5];
    const float* bk  = (const float*)d_in[6];
    const float* Wv  = (const float*)d_in[7];
    const float* bv  = (const float*)d_in[8];
    const float* Wup = (const float*)d_in[9];
    const float* bup = (const float*)d_in[10];
    const float* Wc  = (const float*)d_in[11];
    const float* bc  = (const float*)d_in[12];
    const float* wcq = (const float*)d_in[13];
    const float* bcq = (const float*)d_in[14];
    const float* wck = (const float*)d_in[15];
    const float* bck = (const float*)d_in[16];
    const float* wcv = (const float*)d_in[17];
    const float* bcv = (const float*)d_in[18];

    // A3 staging (18.9 MB bf16 [3][1024][3072]) lives in d_out; gemm_out_up
    // rewrites all of d_out at the end.
    u16* A3 = (u16*)d_out;

    char* wsb = (char*)d_ws;
    // ws layout (bytes):
    //   0        : Wt3  bf16 [3][1024 n][3072 k]  18,874,368
    //   18874368 : Wtc  bf16 [1024][1024]          2,097,152
    //   20971520 : biasT f32 [3][3][1024]             36,864
    //   21008384 : qb   bf16 [64*256][64]          2,097,152
    //   23105536 : kb   bf16 [64*256][64]          2,097,152
    //   25202688 : vt   bf16 [64][80][256]         2,621,440
    //   27824128 : WupT bf16 [64][64]                  8,192
    //   32018432 : ms   bf16 [1024][1024]          2,097,152
    u16*   Wt3   = (u16*)wsb;
    u16*   Wtc   = (u16*)(wsb + 18874368);
    float* biasT = (float*)(wsb + 20971520);
    u16*   qb    = (u16*)(wsb + 21008384);
    u16*   kb    = (u16*)(wsb + 23105536);
    u16*   vt    = (u16*)(wsb + 25202688);
    u16*   WupT  = (u16*)(wsb + 27824128);
    u16*   ms    = (u16*)(wsb + 32018432);

    // 1. weight prep + bias table + WupT + input staging (one dispatch)
    prep_stage<<<4109, 256, 0, stream>>>(q, k, v, Wq, Wk, Wv, Wc, Wup,
                                         wcq, wck, wcv, bcq, bck, bcv,
                                         bq, bk, bv, Wt3, Wtc, biasT, WupT, A3);
    // 2. fused QKV GEMM + V^T pad (784 one-wave blocks, n-band L2-resident mapping)
    gemm_qkv<<<784, 64, 0, stream>>>(A3, Wt3, biasT, qb, kb, vt);
    // 3. MFMA causal attention + fused up-dense -> ms (256 one-wave blocks)
    attn_mfma<<<dim3(4, 64), 64, 0, stream>>>(qb, kb, vt, WupT, bup, ms);
    // 4. final dense + fused 8x upsample -> d_out (256 one-wave blocks)
    gemm_out_up<<<256, 64, 0, stream>>>(ms, Wtc, bc, (float*)d_out);
}